// Round 12
// baseline (193.395 us; speedup 1.0000x reference)
//
#include <hip/hip_runtime.h>

// EGNN layer, round 20: r19 base (190.6 us) with both GEMM kernels
// restructured as B-in-LDS-ONCE (k-sliced layout [k/8][row][8]: fragment
// reads are contiguous 256B quarter-wave bursts, conflict-free, no pad) +
// A direct from global in fragment layout. pgemm barriers 8 -> 1; mlp
// barriers 21 -> 3 (Ts k-sliced + per-wave row banding needs no syncthreads).
// r17 showed B-from-global loses (L2 re-reads); this keeps B LDS-resident
// and only removes the A round-trip + per-k-step barrier drains.
// node_k (60 us proven), init, scatter-fusion unchanged from r19.
// B=4, N=16384, E=65536, DH=128, DM=64.  NB = 65536 global nodes.

typedef unsigned short ushort_t;
typedef __attribute__((ext_vector_type(8))) short bf16x8;
typedef __attribute__((ext_vector_type(4))) float f32x4;
typedef _Float16 h2 __attribute__((ext_vector_type(2)));

__device__ __forceinline__ float fast_rcp(float v) { return __builtin_amdgcn_rcpf(v); }
__device__ __forceinline__ float fast_silu(float v) { return v * fast_rcp(1.0f + __expf(-v)); }
__device__ __forceinline__ ushort_t f2bf(float f) {
    unsigned u = __float_as_uint(f);
    u += 0x7fffu + ((u >> 16) & 1u);
    return (ushort_t)(u >> 16);
}
__device__ __forceinline__ float bf2f(ushort_t b) {
    return __uint_as_float(((unsigned)b) << 16);
}
__device__ __forceinline__ h2 u2h2(unsigned u) {
    union { unsigned u; h2 h; } v; v.u = u; return v.h;
}

// ---------------------------------------------------------------------------
// init: cursor=0 (65536) + weight transforms. 488*256 = 124928 threads exact.
//  W1t  bf16[128][128] : fused pe_w1 cols, k-contiguous
//  Wp1t bf16[128][192] : ph_w1^T
//  Wp2t bf16[128][128] : ph_w2^T
//  w2h  uint[32][64]   : w2h[k2*64+c] = half2(pe_w2[2k2][c], pe_w2[2k2+1][c])
// ---------------------------------------------------------------------------
__global__ __launch_bounds__(256) void init_k(const float* __restrict__ pe_w1,
                                              const float* __restrict__ pe_w2,
                                              const float* __restrict__ ph_w1,
                                              const float* __restrict__ ph_w2,
                                              int* __restrict__ cursor,
                                              ushort_t* __restrict__ W1t,
                                              ushort_t* __restrict__ Wp1t,
                                              ushort_t* __restrict__ Wp2t,
                                              unsigned* __restrict__ w2h) {
    int gg = blockIdx.x * 256 + threadIdx.x;
    if (gg < 65536) { cursor[gg] = 0; return; }
    int g = gg - 65536;
    if (g < 16384) {
        int c = g >> 7, k = g & 127;
        float v = (c < 64) ? pe_w1[k * 64 + c] : pe_w1[(128 + k) * 64 + (c - 64)];
        W1t[g] = f2bf(v);
    } else if (g < 40960) {
        int g2 = g - 16384;
        int n = g2 / 192, k = g2 - n * 192;
        Wp1t[g2] = f2bf(ph_w1[k * 128 + n]);
    } else if (g < 57344) {
        int g3 = g - 40960;
        int n = g3 >> 7, k = g3 & 127;
        Wp2t[g3] = f2bf(ph_w2[k * 128 + n]);
    } else if (g < 59392) {
        int g4 = g - 57344;
        int k2 = g4 >> 6, c = g4 & 63;
        union { unsigned u; _Float16 h[2]; } p;
        p.h[0] = (_Float16)pe_w2[(2 * k2) * 64 + c];
        p.h[1] = (_Float16)pe_w2[(2 * k2 + 1) * 64 + c];
        w2h[g4] = p.u;
    }
}

// ---------------------------------------------------------------------------
// pgemm (blocks 0..511) + scatter (blocks 512..1535), fused launch.
// pgemm: P = h @ W1t^T (bf16 out), emits hb=bf16(h). B in LDS once
// (k-sliced), A direct from global, ONE barrier total.
// ---------------------------------------------------------------------------
template <bool EMIT_BF16>
__global__ __launch_bounds__(256) void pgemm_scatter_k(const float* __restrict__ A0,
                                                       const ushort_t* __restrict__ Wt,
                                                       ushort_t* __restrict__ outP,
                                                       ushort_t* __restrict__ hbout,
                                                       const int* __restrict__ ei,
                                                       int* __restrict__ cursor,
                                                       int* __restrict__ elist) {
    __shared__ ushort_t Bs[16384];                 // [kg=16][row=128][8] = 32 KB
    const int tid = threadIdx.x;

    if (blockIdx.x >= 512) {                       // ---- scatter part
        int e = (blockIdx.x - 512) * 256 + tid;
        int2 sd = ((const int2*)ei)[e];
        int b = e >> 16;
        int gi = (b << 14) + sd.x;
        int gj = (b << 14) + sd.y;
        int slot = atomicAdd(&cursor[gi], 1);
        if (slot < 64) elist[gi * 64 + slot] = gj;
        return;
    }

    const int m0 = blockIdx.x * 128;
    const int wave = tid >> 6;
    const int lane = tid & 63;
    const int lr = lane & 15;
    const int lq = lane >> 4;

    // stage W1t k-sliced: chunk c -> n = c>>4, kg = c&15 (src coalesced)
#pragma unroll
    for (int i = 0; i < 8; i++) {
        int c = tid + i * 256;
        int n = c >> 4, kg = c & 15;
        *(uint4*)&Bs[kg * 1024 + n * 8] = *(const uint4*)(Wt + n * 128 + kg * 8);
    }
    __syncthreads();                               // the ONLY barrier

    f32x4 acc[2][8];
#pragma unroll
    for (int mt = 0; mt < 2; mt++)
#pragma unroll
        for (int nt = 0; nt < 8; nt++) { f32x4 z = {0.f,0.f,0.f,0.f}; acc[mt][nt] = z; }

    for (int k0 = 0; k0 < 128; k0 += 32) {
        bf16x8 af[2];
#pragma unroll
        for (int mt = 0; mt < 2; mt++) {
            int row = m0 + wave * 32 + mt * 16 + lr;
            const float* src = A0 + (size_t)row * 128 + k0 + lq * 8;
            float4 v0 = *(const float4*)src;
            float4 v1 = *(const float4*)(src + 4);
            union { ushort_t s[8]; bf16x8 v; uint4 u; } p;
            p.s[0] = f2bf(v0.x); p.s[1] = f2bf(v0.y);
            p.s[2] = f2bf(v0.z); p.s[3] = f2bf(v0.w);
            p.s[4] = f2bf(v1.x); p.s[5] = f2bf(v1.y);
            p.s[6] = f2bf(v1.z); p.s[7] = f2bf(v1.w);
            if (EMIT_BF16)
                *(uint4*)(hbout + (size_t)row * 128 + k0 + lq * 8) = p.u;
            af[mt] = p.v;
        }
        bf16x8 bfr[8];
        int kg = (k0 >> 3) + lq;
#pragma unroll
        for (int nt = 0; nt < 8; nt++)
            bfr[nt] = *(const bf16x8*)&Bs[kg * 1024 + (nt * 16 + lr) * 8];
#pragma unroll
        for (int mt = 0; mt < 2; mt++)
#pragma unroll
            for (int nt = 0; nt < 8; nt++)
                acc[mt][nt] = __builtin_amdgcn_mfma_f32_16x16x32_bf16(af[mt], bfr[nt], acc[mt][nt], 0, 0, 0);
    }
#pragma unroll
    for (int mt = 0; mt < 2; mt++)
#pragma unroll
        for (int nt = 0; nt < 8; nt++)
#pragma unroll
            for (int r = 0; r < 4; r++) {
                int row = m0 + wave * 32 + mt * 16 + lq * 4 + r;
                int col = nt * 16 + lr;
                outP[(size_t)row * 128 + col] = f2bf(acc[mt][nt][r]);
            }
}

// ---------------------------------------------------------------------------
// node kernel (r16 proven, 60 us): one wave per node, lane = feature,
// register prefetch of next edge's gathers.
// ---------------------------------------------------------------------------
__global__ __launch_bounds__(64, 4) void node_k(const float* __restrict__ x,
                                                const ushort_t* __restrict__ P,
                                                const int* __restrict__ cursor,
                                                const int* __restrict__ elist,
                                                const float* __restrict__ w1,
                                                const float* __restrict__ b1,
                                                const unsigned* __restrict__ w2h,
                                                const float* __restrict__ b2,
                                                const float* __restrict__ pxw,
                                                ushort_t* __restrict__ dh,
                                                float* __restrict__ outx) {
    const int n = blockIdx.x;
    const int lane = threadIdx.x;
    __shared__ __attribute__((aligned(16))) unsigned m_u[32];    // 64 halves
    ushort_t* mh = (ushort_t*)m_u;

    const float w1r = w1[256 * 64 + lane];       // dist2 row of pe_w1
    const float b2v = b2[lane];
    const float pxv = pxw[lane];
    const float Pib = bf2f(P[(size_t)n * 128 + lane]) + b1[lane];
    const float xi0 = x[n * 3 + 0];
    const float xi1 = x[n * 3 + 1];
    const float xi2 = x[n * 3 + 2];

    float dhacc = 0.0f;
    float dxp0 = 0.0f, dxp1 = 0.0f, dxp2 = 0.0f;
    const int dg = min(cursor[n], 64);
    const int base = n * 64;

    int gj0 = (dg > 0) ? elist[base] : 0;
    float Pj = bf2f(P[(size_t)gj0 * 128 + 64 + lane]);
    float xj0 = x[gj0 * 3 + 0];
    float xj1 = x[gj0 * 3 + 1];
    float xj2 = x[gj0 * 3 + 2];

    for (int t = 0; t < dg; t++) {
        int gjn = (t + 1 < dg) ? elist[base + t + 1] : 0;
        float Pjn = bf2f(P[(size_t)gjn * 128 + 64 + lane]);
        float xn0 = x[gjn * 3 + 0];
        float xn1 = x[gjn * 3 + 1];
        float xn2 = x[gjn * 3 + 2];

        float ddx = xi0 - xj0;
        float ddy = xi1 - xj1;
        float ddz = xi2 - xj2;
        float d2 = fmaxf(ddx * ddx + ddy * ddy + ddz * ddz, 1e-12f);
        float m = fast_silu(Pib + Pj + d2 * w1r);
        __builtin_amdgcn_wave_barrier();
        union { ushort_t s; _Float16 h; } mc;
        mc.h = (_Float16)m;
        mh[lane] = mc.s;
        __builtin_amdgcn_wave_barrier();
        float s0 = b2v, s1 = 0.0f, s2 = 0.0f, s3 = 0.0f;
#pragma unroll
        for (int q = 0; q < 8; q++) {
            uint4 mm = *(const uint4*)&m_u[q * 4];               // ds_read_b128 broadcast
            s0 = __builtin_amdgcn_fdot2(u2h2(mm.x), u2h2(w2h[(4 * q + 0) * 64 + lane]), s0, false);
            s1 = __builtin_amdgcn_fdot2(u2h2(mm.y), u2h2(w2h[(4 * q + 1) * 64 + lane]), s1, false);
            s2 = __builtin_amdgcn_fdot2(u2h2(mm.z), u2h2(w2h[(4 * q + 2) * 64 + lane]), s2, false);
            s3 = __builtin_amdgcn_fdot2(u2h2(mm.w), u2h2(w2h[(4 * q + 3) * 64 + lane]), s3, false);
        }
        __builtin_amdgcn_wave_barrier();
        float m2 = fast_silu((s0 + s1) + (s2 + s3));
        dhacc += m2;
        float c = m2 * pxv * fast_rcp(sqrtf(d2) + 1e-8f);
        dxp0 = fmaf(c, ddx, dxp0);
        dxp1 = fmaf(c, ddy, dxp1);
        dxp2 = fmaf(c, ddz, dxp2);

        Pj = Pjn; xj0 = xn0; xj1 = xn1; xj2 = xn2;
    }

    dh[(size_t)n * 64 + lane] = f2bf(dhacc);                 // coalesced

    for (int off = 32; off; off >>= 1) {
        dxp0 += __shfl_down(dxp0, off);
        dxp1 += __shfl_down(dxp1, off);
        dxp2 += __shfl_down(dxp2, off);
    }
    if (lane == 0) {
        outx[n * 3 + 0] = xi0 + dxp0;
        outx[n * 3 + 1] = xi1 + dxp1;
        outx[n * 3 + 2] = xi2 + dxp2;
    }
}

// ---------------------------------------------------------------------------
// Fused node MLP: out_h = h + silu([h|dh]@W1 + b1) @ W2 + b2.
// B (Wp1t then Wp2t) in LDS once per phase, k-sliced. A direct from global.
// Ts k-sliced, per-wave row banding -> no syncthreads around it.
// Barriers: 3 total (Ws load, Ws swap x2).
// ---------------------------------------------------------------------------
template <bool USE_HB>
__global__ __launch_bounds__(256) void mlp_fused_k(const float* __restrict__ h,
                                                   const ushort_t* __restrict__ hb,
                                                   const ushort_t* __restrict__ dh,
                                                   const ushort_t* __restrict__ Wp1t,
                                                   const float* __restrict__ b1,
                                                   const ushort_t* __restrict__ Wp2t,
                                                   const float* __restrict__ b2,
                                                   float* __restrict__ outh) {
    __shared__ ushort_t Ws[24576];   // phase1: [kg=24][128][8] = 48 KB; phase2: 16 kg
    __shared__ ushort_t Ts[16384];   // [kg=16][128][8] = 32 KB
    const int tid = threadIdx.x;
    const int m0 = blockIdx.x * 128;
    const int wave = tid >> 6;
    const int lane = tid & 63;
    const int lr = lane & 15;
    const int lq = lane >> 4;

    // stage Wp1t k-sliced: chunk c -> kg = c>>7 (0..23), n = c&127
#pragma unroll
    for (int i = 0; i < 12; i++) {
        int c = tid + i * 256;
        int kg = c >> 7, n = c & 127;
        *(uint4*)&Ws[kg * 1024 + n * 8] = *(const uint4*)(Wp1t + (size_t)n * 192 + kg * 8);
    }
    __syncthreads();                               // barrier 1

    // ---- phase 1: t = silu([h|dh] @ W1 + b1), K = 192, A direct
    f32x4 acc[2][8];
#pragma unroll
    for (int mt = 0; mt < 2; mt++)
#pragma unroll
        for (int nt = 0; nt < 8; nt++) { f32x4 z = {0.f,0.f,0.f,0.f}; acc[mt][nt] = z; }

    for (int k0 = 0; k0 < 192; k0 += 32) {
        bf16x8 af[2];
#pragma unroll
        for (int mt = 0; mt < 2; mt++) {
            int row = m0 + wave * 32 + mt * 16 + lr;
            int k = k0 + lq * 8;
            if (k >= 128) {
                af[mt] = *(const bf16x8*)&dh[(size_t)row * 64 + (k - 128)];
            } else if (USE_HB) {
                af[mt] = *(const bf16x8*)&hb[(size_t)row * 128 + k];
            } else {
                const float* src = h + (size_t)row * 128 + k;
                float4 v0 = *(const float4*)src;
                float4 v1 = *(const float4*)(src + 4);
                union { ushort_t s[8]; bf16x8 v; } p;
                p.s[0] = f2bf(v0.x); p.s[1] = f2bf(v0.y);
                p.s[2] = f2bf(v0.z); p.s[3] = f2bf(v0.w);
                p.s[4] = f2bf(v1.x); p.s[5] = f2bf(v1.y);
                p.s[6] = f2bf(v1.z); p.s[7] = f2bf(v1.w);
                af[mt] = p.v;
            }
        }
        bf16x8 bfr[8];
        int kg = (k0 >> 3) + lq;
#pragma unroll
        for (int nt = 0; nt < 8; nt++)
            bfr[nt] = *(const bf16x8*)&Ws[kg * 1024 + (nt * 16 + lr) * 8];
#pragma unroll
        for (int mt = 0; mt < 2; mt++)
#pragma unroll
            for (int nt = 0; nt < 8; nt++)
                acc[mt][nt] = __builtin_amdgcn_mfma_f32_16x16x32_bf16(af[mt], bfr[nt], acc[mt][nt], 0, 0, 0);
    }
    // epilogue 1: silu -> Ts (k-sliced; rows wave*32..+31 are wave-private)
#pragma unroll
    for (int mt = 0; mt < 2; mt++)
#pragma unroll
        for (int nt = 0; nt < 8; nt++)
#pragma unroll
            for (int r = 0; r < 4; r++) {
                int row = wave * 32 + mt * 16 + lq * 4 + r;
                int col = nt * 16 + lr;
                Ts[(col >> 3) * 1024 + row * 8 + (col & 7)] =
                    f2bf(fast_silu(acc[mt][nt][r] + b1[col]));
            }
    __builtin_amdgcn_wave_barrier();

    // swap Ws -> Wp2t (all waves must be done reading Wp1t)
    __syncthreads();                               // barrier 2
#pragma unroll
    for (int i = 0; i < 8; i++) {
        int c = tid + i * 256;
        int kg = c >> 7, n = c & 127;
        *(uint4*)&Ws[kg * 1024 + n * 8] = *(const uint4*)(Wp2t + (size_t)n * 128 + kg * 8);
    }
    __syncthreads();                               // barrier 3

    // ---- phase 2: out = t @ W2 + b2 + h, K = 128, A from Ts (own band)
    f32x4 acc2[2][8];
#pragma unroll
    for (int mt = 0; mt < 2; mt++)
#pragma unroll
        for (int nt = 0; nt < 8; nt++) { f32x4 z = {0.f,0.f,0.f,0.f}; acc2[mt][nt] = z; }

    for (int k0 = 0; k0 < 128; k0 += 32) {
        bf16x8 af[2], bfr[8];
        int kg = (k0 >> 3) + lq;
#pragma unroll
        for (int mt = 0; mt < 2; mt++)
            af[mt] = *(const bf16x8*)&Ts[kg * 1024 + (wave * 32 + mt * 16 + lr) * 8];
#pragma unroll
        for (int nt = 0; nt < 8; nt++)
            bfr[nt] = *(const bf16x8*)&Ws[kg * 1024 + (nt * 16 + lr) * 8];
#pragma unroll
        for (int mt = 0; mt < 2; mt++)
#pragma unroll
            for (int nt = 0; nt < 8; nt++)
                acc2[mt][nt] = __builtin_amdgcn_mfma_f32_16x16x32_bf16(af[mt], bfr[nt], acc2[mt][nt], 0, 0, 0);
    }
    // epilogue 2: + b2 + h residual
#pragma unroll
    for (int mt = 0; mt < 2; mt++)
#pragma unroll
        for (int nt = 0; nt < 8; nt++)
#pragma unroll
            for (int r = 0; r < 4; r++) {
                int row = m0 + wave * 32 + mt * 16 + lq * 4 + r;
                int col = nt * 16 + lr;
                float v = acc2[mt][nt][r] + b2[col];
                if (USE_HB) v += bf2f(hb[(size_t)row * 128 + col]);
                else        v += h[(size_t)row * 128 + col];
                outh[(size_t)row * 128 + col] = v;
            }
}

// ---------------------------------------------------------------------------
extern "C" void kernel_launch(void* const* d_in, const int* in_sizes, int n_in,
                              void* d_out, int out_size, void* d_ws, size_t ws_size,
                              hipStream_t stream) {
    const float* x     = (const float*)d_in[0];
    const float* h     = (const float*)d_in[1];
    const int*   ei    = (const int*)d_in[2];
    const float* pe_w1 = (const float*)d_in[3];
    const float* pe_b1 = (const float*)d_in[4];
    const float* pe_w2 = (const float*)d_in[5];
    const float* pe_b2 = (const float*)d_in[6];
    const float* px_w  = (const float*)d_in[7];
    const float* ph_w1 = (const float*)d_in[8];
    const float* ph_b1 = (const float*)d_in[9];
    const float* ph_w2 = (const float*)d_in[10];
    const float* ph_b2 = (const float*)d_in[11];

    float* outx = (float*)d_out;                    // 4*16384*3
    float* outh = (float*)d_out + 196608;           // 4*16384*128

    // ws layout
    ushort_t* P    = (ushort_t*)d_ws;                     // 65536*128 bf16
    ushort_t* dh   = P + (size_t)65536 * 128;             // 65536*64 bf16
    int* cursor    = (int*)(dh + (size_t)65536 * 64);     // 65536 i32
    int* elist     = cursor + 65536;                      // 65536*64 i32 (16 MB)
    ushort_t* W1t  = (ushort_t*)(elist + (size_t)65536 * 64);  // 128*128 bf16
    ushort_t* Wp1t = W1t + 16384;                         // 128*192 bf16
    ushort_t* Wp2t = Wp1t + 24576;                        // 128*128 bf16
    unsigned* w2h  = (unsigned*)(Wp2t + 16384);           // 32*64 uint (in 16KB slot)
    ushort_t* hb   = (ushort_t*)(w2h + 4096);             // 65536*128 bf16 (16 MB)
    size_t need_hb = (size_t)((char*)(hb + (size_t)65536 * 128) - (char*)d_ws);
    const bool use_hb = ws_size >= need_hb;

    init_k<<<488, 256, 0, stream>>>(pe_w1, pe_w2, ph_w1, ph_w2,
                                    cursor, W1t, Wp1t, Wp2t, w2h);
    if (use_hb)
        pgemm_scatter_k<true><<<1536, 256, 0, stream>>>(h, W1t, P, hb,
                                                        ei, cursor, elist);
    else
        pgemm_scatter_k<false><<<1536, 256, 0, stream>>>(h, W1t, P, nullptr,
                                                         ei, cursor, elist);
    node_k<<<65536, 64, 0, stream>>>(x, P, cursor, elist,
                                     pe_w1, pe_b1, w2h, pe_b2, px_w,
                                     dh, outx);
    if (use_hb)
        mlp_fused_k<true><<<512, 256, 0, stream>>>(h, hb, dh, Wp1t, ph_b1,
                                                   Wp2t, ph_b2, outh);
    else
        mlp_fused_k<false><<<512, 256, 0, stream>>>(h, nullptr, dh, Wp1t, ph_b1,
                                                    Wp2t, ph_b2, outh);
}

// Round 13
// 191.782 us; speedup vs baseline: 1.0084x; 1.0084x over previous
//
#include <hip/hip_runtime.h>

// EGNN layer, round 21: pgemm/mlp re-partitioned to 512-thread blocks
// (8 waves, one 16-row band per wave, 1x8 acc) — same tiles, same LDS, but
// 16 waves/CU instead of 8. Theory: three neutral GEMM restructures (r17,
// r20) mean they're latency-bound at 8 waves/CU, not barrier- or
// staging-bound; double TLP is the lever. cursor reset via hipMemsetAsync;
// init_k shrinks to the 232-block weight transforms.
// node_k (60 us proven floor), scatter fusion unchanged.
// B=4, N=16384, E=65536, DH=128, DM=64.  NB = 65536 global nodes.

typedef unsigned short ushort_t;
typedef __attribute__((ext_vector_type(8))) short bf16x8;
typedef __attribute__((ext_vector_type(4))) float f32x4;
typedef _Float16 h2 __attribute__((ext_vector_type(2)));

__device__ __forceinline__ float fast_rcp(float v) { return __builtin_amdgcn_rcpf(v); }
__device__ __forceinline__ float fast_silu(float v) { return v * fast_rcp(1.0f + __expf(-v)); }
__device__ __forceinline__ ushort_t f2bf(float f) {
    unsigned u = __float_as_uint(f);
    u += 0x7fffu + ((u >> 16) & 1u);
    return (ushort_t)(u >> 16);
}
__device__ __forceinline__ float bf2f(ushort_t b) {
    return __uint_as_float(((unsigned)b) << 16);
}
__device__ __forceinline__ h2 u2h2(unsigned u) {
    union { unsigned u; h2 h; } v; v.u = u; return v.h;
}

// ---------------------------------------------------------------------------
// init: weight transforms only (cursor is zeroed by hipMemsetAsync).
// 232*256 = 59392 threads exact.
//  W1t  bf16[128][128] : fused pe_w1 cols, k-contiguous
//  Wp1t bf16[128][192] : ph_w1^T
//  Wp2t bf16[128][128] : ph_w2^T
//  w2h  uint[32][64]   : w2h[k2*64+c] = half2(pe_w2[2k2][c], pe_w2[2k2+1][c])
// ---------------------------------------------------------------------------
__global__ __launch_bounds__(256) void init_k(const float* __restrict__ pe_w1,
                                              const float* __restrict__ pe_w2,
                                              const float* __restrict__ ph_w1,
                                              const float* __restrict__ ph_w2,
                                              ushort_t* __restrict__ W1t,
                                              ushort_t* __restrict__ Wp1t,
                                              ushort_t* __restrict__ Wp2t,
                                              unsigned* __restrict__ w2h) {
    int g = blockIdx.x * 256 + threadIdx.x;
    if (g < 16384) {
        int c = g >> 7, k = g & 127;
        float v = (c < 64) ? pe_w1[k * 64 + c] : pe_w1[(128 + k) * 64 + (c - 64)];
        W1t[g] = f2bf(v);
    } else if (g < 40960) {
        int g2 = g - 16384;
        int n = g2 / 192, k = g2 - n * 192;
        Wp1t[g2] = f2bf(ph_w1[k * 128 + n]);
    } else if (g < 57344) {
        int g3 = g - 40960;
        int n = g3 >> 7, k = g3 & 127;
        Wp2t[g3] = f2bf(ph_w2[k * 128 + n]);
    } else if (g < 59392) {
        int g4 = g - 57344;
        int k2 = g4 >> 6, c = g4 & 63;
        union { unsigned u; _Float16 h[2]; } p;
        p.h[0] = (_Float16)pe_w2[(2 * k2) * 64 + c];
        p.h[1] = (_Float16)pe_w2[(2 * k2 + 1) * 64 + c];
        w2h[g4] = p.u;
    }
}

// ---------------------------------------------------------------------------
// pgemm (blocks 0..511) + scatter (blocks 512..1023), fused 512-thread launch.
// pgemm: 8 waves, wave w owns rows m0+w*16..+15 (1x8 acc). B in LDS once
// (k-sliced [kg][row][8]), A direct from global, ONE barrier.
// scatter: 512 threads/block x 512 blocks = 262144 edges.
// ---------------------------------------------------------------------------
template <bool EMIT_BF16>
__global__ __launch_bounds__(512) void pgemm_scatter_k(const float* __restrict__ A0,
                                                       const ushort_t* __restrict__ Wt,
                                                       ushort_t* __restrict__ outP,
                                                       ushort_t* __restrict__ hbout,
                                                       const int* __restrict__ ei,
                                                       int* __restrict__ cursor,
                                                       int* __restrict__ elist) {
    __shared__ ushort_t Bs[16384];                 // [kg=16][row=128][8] = 32 KB
    const int tid = threadIdx.x;

    if (blockIdx.x >= 512) {                       // ---- scatter part
        int e = (blockIdx.x - 512) * 512 + tid;
        int2 sd = ((const int2*)ei)[e];
        int b = e >> 16;
        int gi = (b << 14) + sd.x;
        int gj = (b << 14) + sd.y;
        int slot = atomicAdd(&cursor[gi], 1);
        if (slot < 64) elist[gi * 64 + slot] = gj;
        return;
    }

    const int m0 = blockIdx.x * 128;
    const int wave = tid >> 6;                     // 0..7
    const int lane = tid & 63;
    const int lr = lane & 15;
    const int lq = lane >> 4;

    // stage W1t k-sliced: chunk c -> n = c>>4, kg = c&15
#pragma unroll
    for (int i = 0; i < 4; i++) {
        int c = tid + i * 512;
        int n = c >> 4, kg = c & 15;
        *(uint4*)&Bs[kg * 1024 + n * 8] = *(const uint4*)(Wt + n * 128 + kg * 8);
    }
    __syncthreads();                               // the ONLY barrier

    f32x4 acc[8];
#pragma unroll
    for (int nt = 0; nt < 8; nt++) { f32x4 z = {0.f,0.f,0.f,0.f}; acc[nt] = z; }

    for (int k0 = 0; k0 < 128; k0 += 32) {
        int row = m0 + wave * 16 + lr;
        const float* src = A0 + (size_t)row * 128 + k0 + lq * 8;
        float4 v0 = *(const float4*)src;
        float4 v1 = *(const float4*)(src + 4);
        union { ushort_t s[8]; bf16x8 v; uint4 u; } p;
        p.s[0] = f2bf(v0.x); p.s[1] = f2bf(v0.y);
        p.s[2] = f2bf(v0.z); p.s[3] = f2bf(v0.w);
        p.s[4] = f2bf(v1.x); p.s[5] = f2bf(v1.y);
        p.s[6] = f2bf(v1.z); p.s[7] = f2bf(v1.w);
        if (EMIT_BF16)
            *(uint4*)(hbout + (size_t)row * 128 + k0 + lq * 8) = p.u;
        bf16x8 af = p.v;
        bf16x8 bfr[8];
        int kg = (k0 >> 3) + lq;
#pragma unroll
        for (int nt = 0; nt < 8; nt++)
            bfr[nt] = *(const bf16x8*)&Bs[kg * 1024 + (nt * 16 + lr) * 8];
#pragma unroll
        for (int nt = 0; nt < 8; nt++)
            acc[nt] = __builtin_amdgcn_mfma_f32_16x16x32_bf16(af, bfr[nt], acc[nt], 0, 0, 0);
    }
#pragma unroll
    for (int nt = 0; nt < 8; nt++)
#pragma unroll
        for (int r = 0; r < 4; r++) {
            int row = m0 + wave * 16 + lq * 4 + r;
            int col = nt * 16 + lr;
            outP[(size_t)row * 128 + col] = f2bf(acc[nt][r]);
        }
}

// ---------------------------------------------------------------------------
// node kernel (r16 proven, 60 us): one wave per node, lane = feature,
// register prefetch of next edge's gathers.
// ---------------------------------------------------------------------------
__global__ __launch_bounds__(64, 4) void node_k(const float* __restrict__ x,
                                                const ushort_t* __restrict__ P,
                                                const int* __restrict__ cursor,
                                                const int* __restrict__ elist,
                                                const float* __restrict__ w1,
                                                const float* __restrict__ b1,
                                                const unsigned* __restrict__ w2h,
                                                const float* __restrict__ b2,
                                                const float* __restrict__ pxw,
                                                ushort_t* __restrict__ dh,
                                                float* __restrict__ outx) {
    const int n = blockIdx.x;
    const int lane = threadIdx.x;
    __shared__ __attribute__((aligned(16))) unsigned m_u[32];    // 64 halves
    ushort_t* mh = (ushort_t*)m_u;

    const float w1r = w1[256 * 64 + lane];       // dist2 row of pe_w1
    const float b2v = b2[lane];
    const float pxv = pxw[lane];
    const float Pib = bf2f(P[(size_t)n * 128 + lane]) + b1[lane];
    const float xi0 = x[n * 3 + 0];
    const float xi1 = x[n * 3 + 1];
    const float xi2 = x[n * 3 + 2];

    float dhacc = 0.0f;
    float dxp0 = 0.0f, dxp1 = 0.0f, dxp2 = 0.0f;
    const int dg = min(cursor[n], 64);
    const int base = n * 64;

    int gj0 = (dg > 0) ? elist[base] : 0;
    float Pj = bf2f(P[(size_t)gj0 * 128 + 64 + lane]);
    float xj0 = x[gj0 * 3 + 0];
    float xj1 = x[gj0 * 3 + 1];
    float xj2 = x[gj0 * 3 + 2];

    for (int t = 0; t < dg; t++) {
        int gjn = (t + 1 < dg) ? elist[base + t + 1] : 0;
        float Pjn = bf2f(P[(size_t)gjn * 128 + 64 + lane]);
        float xn0 = x[gjn * 3 + 0];
        float xn1 = x[gjn * 3 + 1];
        float xn2 = x[gjn * 3 + 2];

        float ddx = xi0 - xj0;
        float ddy = xi1 - xj1;
        float ddz = xi2 - xj2;
        float d2 = fmaxf(ddx * ddx + ddy * ddy + ddz * ddz, 1e-12f);
        float m = fast_silu(Pib + Pj + d2 * w1r);
        __builtin_amdgcn_wave_barrier();
        union { ushort_t s; _Float16 h; } mc;
        mc.h = (_Float16)m;
        mh[lane] = mc.s;
        __builtin_amdgcn_wave_barrier();
        float s0 = b2v, s1 = 0.0f, s2 = 0.0f, s3 = 0.0f;
#pragma unroll
        for (int q = 0; q < 8; q++) {
            uint4 mm = *(const uint4*)&m_u[q * 4];               // ds_read_b128 broadcast
            s0 = __builtin_amdgcn_fdot2(u2h2(mm.x), u2h2(w2h[(4 * q + 0) * 64 + lane]), s0, false);
            s1 = __builtin_amdgcn_fdot2(u2h2(mm.y), u2h2(w2h[(4 * q + 1) * 64 + lane]), s1, false);
            s2 = __builtin_amdgcn_fdot2(u2h2(mm.z), u2h2(w2h[(4 * q + 2) * 64 + lane]), s2, false);
            s3 = __builtin_amdgcn_fdot2(u2h2(mm.w), u2h2(w2h[(4 * q + 3) * 64 + lane]), s3, false);
        }
        __builtin_amdgcn_wave_barrier();
        float m2 = fast_silu((s0 + s1) + (s2 + s3));
        dhacc += m2;
        float c = m2 * pxv * fast_rcp(sqrtf(d2) + 1e-8f);
        dxp0 = fmaf(c, ddx, dxp0);
        dxp1 = fmaf(c, ddy, dxp1);
        dxp2 = fmaf(c, ddz, dxp2);

        Pj = Pjn; xj0 = xn0; xj1 = xn1; xj2 = xn2;
    }

    dh[(size_t)n * 64 + lane] = f2bf(dhacc);                 // coalesced

    for (int off = 32; off; off >>= 1) {
        dxp0 += __shfl_down(dxp0, off);
        dxp1 += __shfl_down(dxp1, off);
        dxp2 += __shfl_down(dxp2, off);
    }
    if (lane == 0) {
        outx[n * 3 + 0] = xi0 + dxp0;
        outx[n * 3 + 1] = xi1 + dxp1;
        outx[n * 3 + 2] = xi2 + dxp2;
    }
}

// ---------------------------------------------------------------------------
// Fused node MLP, 512 threads (8 waves, 16-row band per wave, 1x8 acc).
// B (Wp1t then Wp2t) in LDS once per phase, k-sliced. A direct from global.
// Ts k-sliced, per-wave row banding. Barriers: 3 total.
// ---------------------------------------------------------------------------
template <bool USE_HB>
__global__ __launch_bounds__(512) void mlp_fused_k(const float* __restrict__ h,
                                                   const ushort_t* __restrict__ hb,
                                                   const ushort_t* __restrict__ dh,
                                                   const ushort_t* __restrict__ Wp1t,
                                                   const float* __restrict__ b1,
                                                   const ushort_t* __restrict__ Wp2t,
                                                   const float* __restrict__ b2,
                                                   float* __restrict__ outh) {
    __shared__ ushort_t Ws[24576];   // phase1: [kg=24][128][8] = 48 KB; phase2: 16 kg
    __shared__ ushort_t Ts[16384];   // [kg=16][128][8] = 32 KB
    const int tid = threadIdx.x;
    const int m0 = blockIdx.x * 128;
    const int wave = tid >> 6;       // 0..7
    const int lane = tid & 63;
    const int lr = lane & 15;
    const int lq = lane >> 4;

    // stage Wp1t k-sliced: chunk c -> kg = c>>7 (0..23), n = c&127
#pragma unroll
    for (int i = 0; i < 6; i++) {
        int c = tid + i * 512;
        int kg = c >> 7, n = c & 127;
        *(uint4*)&Ws[kg * 1024 + n * 8] = *(const uint4*)(Wp1t + (size_t)n * 192 + kg * 8);
    }
    __syncthreads();                               // barrier 1

    // ---- phase 1: t = silu([h|dh] @ W1 + b1), K = 192, A direct
    f32x4 acc[8];
#pragma unroll
    for (int nt = 0; nt < 8; nt++) { f32x4 z = {0.f,0.f,0.f,0.f}; acc[nt] = z; }

    for (int k0 = 0; k0 < 192; k0 += 32) {
        int row = m0 + wave * 16 + lr;
        int k = k0 + lq * 8;
        bf16x8 af;
        if (k >= 128) {
            af = *(const bf16x8*)&dh[(size_t)row * 64 + (k - 128)];
        } else if (USE_HB) {
            af = *(const bf16x8*)&hb[(size_t)row * 128 + k];
        } else {
            const float* src = h + (size_t)row * 128 + k;
            float4 v0 = *(const float4*)src;
            float4 v1 = *(const float4*)(src + 4);
            union { ushort_t s[8]; bf16x8 v; } p;
            p.s[0] = f2bf(v0.x); p.s[1] = f2bf(v0.y);
            p.s[2] = f2bf(v0.z); p.s[3] = f2bf(v0.w);
            p.s[4] = f2bf(v1.x); p.s[5] = f2bf(v1.y);
            p.s[6] = f2bf(v1.z); p.s[7] = f2bf(v1.w);
            af = p.v;
        }
        bf16x8 bfr[8];
        int kg = (k0 >> 3) + lq;
#pragma unroll
        for (int nt = 0; nt < 8; nt++)
            bfr[nt] = *(const bf16x8*)&Ws[kg * 1024 + (nt * 16 + lr) * 8];
#pragma unroll
        for (int nt = 0; nt < 8; nt++)
            acc[nt] = __builtin_amdgcn_mfma_f32_16x16x32_bf16(af, bfr[nt], acc[nt], 0, 0, 0);
    }
    // epilogue 1: silu -> Ts (k-sliced; rows wave*16..+15 are wave-private)
#pragma unroll
    for (int nt = 0; nt < 8; nt++)
#pragma unroll
        for (int r = 0; r < 4; r++) {
            int row = wave * 16 + lq * 4 + r;
            int col = nt * 16 + lr;
            Ts[(col >> 3) * 1024 + row * 8 + (col & 7)] =
                f2bf(fast_silu(acc[nt][r] + b1[col]));
        }
    __builtin_amdgcn_wave_barrier();

    // swap Ws -> Wp2t (all waves must be done reading Wp1t)
    __syncthreads();                               // barrier 2
#pragma unroll
    for (int i = 0; i < 4; i++) {
        int c = tid + i * 512;
        int kg = c >> 7, n = c & 127;
        *(uint4*)&Ws[kg * 1024 + n * 8] = *(const uint4*)(Wp2t + (size_t)n * 128 + kg * 8);
    }
    __syncthreads();                               // barrier 3

    // ---- phase 2: out = t @ W2 + b2 + h, K = 128, A from Ts (own band)
    f32x4 acc2[8];
#pragma unroll
    for (int nt = 0; nt < 8; nt++) { f32x4 z = {0.f,0.f,0.f,0.f}; acc2[nt] = z; }

    for (int k0 = 0; k0 < 128; k0 += 32) {
        int kg = (k0 >> 3) + lq;
        bf16x8 af = *(const bf16x8*)&Ts[kg * 1024 + (wave * 16 + lr) * 8];
        bf16x8 bfr[8];
#pragma unroll
        for (int nt = 0; nt < 8; nt++)
            bfr[nt] = *(const bf16x8*)&Ws[kg * 1024 + (nt * 16 + lr) * 8];
#pragma unroll
        for (int nt = 0; nt < 8; nt++)
            acc2[nt] = __builtin_amdgcn_mfma_f32_16x16x32_bf16(af, bfr[nt], acc2[nt], 0, 0, 0);
    }
    // epilogue 2: + b2 + h residual
#pragma unroll
    for (int nt = 0; nt < 8; nt++)
#pragma unroll
        for (int r = 0; r < 4; r++) {
            int row = m0 + wave * 16 + lq * 4 + r;
            int col = nt * 16 + lr;
            float v = acc2[nt][r] + b2[col];
            if (USE_HB) v += bf2f(hb[(size_t)row * 128 + col]);
            else        v += h[(size_t)row * 128 + col];
            outh[(size_t)row * 128 + col] = v;
        }
}

// ---------------------------------------------------------------------------
extern "C" void kernel_launch(void* const* d_in, const int* in_sizes, int n_in,
                              void* d_out, int out_size, void* d_ws, size_t ws_size,
                              hipStream_t stream) {
    const float* x     = (const float*)d_in[0];
    const float* h     = (const float*)d_in[1];
    const int*   ei    = (const int*)d_in[2];
    const float* pe_w1 = (const float*)d_in[3];
    const float* pe_b1 = (const float*)d_in[4];
    const float* pe_w2 = (const float*)d_in[5];
    const float* pe_b2 = (const float*)d_in[6];
    const float* px_w  = (const float*)d_in[7];
    const float* ph_w1 = (const float*)d_in[8];
    const float* ph_b1 = (const float*)d_in[9];
    const float* ph_w2 = (const float*)d_in[10];
    const float* ph_b2 = (const float*)d_in[11];

    float* outx = (float*)d_out;                    // 4*16384*3
    float* outh = (float*)d_out + 196608;           // 4*16384*128

    // ws layout
    ushort_t* P    = (ushort_t*)d_ws;                     // 65536*128 bf16
    ushort_t* dh   = P + (size_t)65536 * 128;             // 65536*64 bf16
    int* cursor    = (int*)(dh + (size_t)65536 * 64);     // 65536 i32
    int* elist     = cursor + 65536;                      // 65536*64 i32 (16 MB)
    ushort_t* W1t  = (ushort_t*)(elist + (size_t)65536 * 64);  // 128*128 bf16
    ushort_t* Wp1t = W1t + 16384;                         // 128*192 bf16
    ushort_t* Wp2t = Wp1t + 24576;                        // 128*128 bf16
    unsigned* w2h  = (unsigned*)(Wp2t + 16384);           // 32*64 uint (in 16KB slot)
    ushort_t* hb   = (ushort_t*)(w2h + 4096);             // 65536*128 bf16 (16 MB)
    size_t need_hb = (size_t)((char*)(hb + (size_t)65536 * 128) - (char*)d_ws);
    const bool use_hb = ws_size >= need_hb;

    hipMemsetAsync(cursor, 0, 65536 * sizeof(int), stream);
    init_k<<<232, 256, 0, stream>>>(pe_w1, pe_w2, ph_w1, ph_w2,
                                    W1t, Wp1t, Wp2t, w2h);
    if (use_hb)
        pgemm_scatter_k<true><<<1024, 512, 0, stream>>>(h, W1t, P, hb,
                                                        ei, cursor, elist);
    else
        pgemm_scatter_k<false><<<1024, 512, 0, stream>>>(h, W1t, P, nullptr,
                                                         ei, cursor, elist);
    node_k<<<65536, 64, 0, stream>>>(x, P, cursor, elist,
                                     pe_w1, pe_b1, w2h, pe_b2, px_w,
                                     dh, outx);
    if (use_hb)
        mlp_fused_k<true><<<512, 512, 0, stream>>>(h, hb, dh, Wp1t, ph_b1,
                                                   Wp2t, ph_b2, outh);
    else
        mlp_fused_k<false><<<512, 512, 0, stream>>>(h, nullptr, dh, Wp1t, ph_b1,
                                                    Wp2t, ph_b2, outh);
}